// Round 5
// baseline (700.536 us; speedup 1.0000x reference)
//
#include <hip/hip_runtime.h>
#include <stdint.h>

// Quantized vector-matrix multiply: out[n] = sum_k (x[k]-Xzp)*Xs * (y[k,n]-Yzp)*Ys
// Exact-integer reformulation:
//   out[n] = Xs*Ys * ( sum_k xs[k]*y[k,n] - Yzp*sum_k xs[k] ),  xs = x - X_ZP
//
// R9 RESUBMIT (R4 bench was an infra failure -- container died before running;
// no counters, no pass/fail on the kernel). HYBRID READ-PATH PROBE, unchanged:
// Four rounds of pattern/occupancy/cache-mode variants all cap at ~1.7 TB/s
// effective read BW -- consistent with a per-CU outstanding-read-line limit on
// the vector-L1 return path (~64 lines x 64 B / ~600 ns loaded latency =
// 6.8 GB/s/CU = 1.7 TB/s chip), NOT scheduling. Writes (no return path) hit
// 6.4 TB/s. The one untried lever: global_load_lds LDS-DMA, whose completions
// land in LDS rather than the VGPR return queue. Per super-iteration (4 rows):
// 2 rows stream via a barrier-free DMA pipeline (each wave stages+consumes its
// own 1 KiB quarter -> no __syncthreads; double-buffered one super-iter ahead)
// while 2 rows go via plain direct loads -- both paths in flight at once. If
// DMA capacity is separate, read BW roughly doubles; if unified, ~unchanged
// (the builtin is compiler-tracked, so worst case is extra waits, not
// corruption).

constexpr int K = 8192;
constexpr int N = 16384;
constexpr float X_SCALE = 0.0215f;
constexpr int   X_ZP    = -25;
constexpr float Y_SCALE = 0.0176f;
constexpr int   Y_ZP    = 18;

constexpr int BLOCK = 256;
constexpr int COLS_PER_BLOCK = 1024;           // int32 columns per block (4 KiB/row)
constexpr int NBLK_N = N / COLS_PER_BLOCK;     // 16
constexpr int SPLIT_K = 128;                   // 2048 blocks -> 8 blocks/CU
constexpr int KCHUNK = K / SPLIT_K;            // 64 rows per block
constexpr int N4 = N / 4;

typedef int ivec4 __attribute__((ext_vector_type(4)));

#define AS1 __attribute__((address_space(1)))
#define AS3 __attribute__((address_space(3)))

__global__ __launch_bounds__(BLOCK, 8) void qgemv_partial(const int* __restrict__ x,
                                                          const int* __restrict__ y,
                                                          ivec4* __restrict__ ws) {
    __shared__ int xs[KCHUNK];
    __shared__ int dbuf[2][2][COLS_PER_BLOCK];   // 2 bufs x 2 rows x 4 KiB = 16 KiB

    const int tid = threadIdx.x;
    const int nb = blockIdx.x % NBLK_N;
    const int kc = blockIdx.x / NBLK_N;
    const int k0 = kc * KCHUNK;

    if (tid < KCHUNK) xs[tid] = x[k0 + tid] - X_ZP;
    __syncthreads();

    // Row r of this block's stripe starts at yrow + r*N; thread's 16 B slice at +tid*4.
    const int* yrow = y + (size_t)k0 * N + nb * COLS_PER_BLOCK;
    // Wave-uniform LDS quarter base: wave w owns ints [w*256, (w+1)*256) of each row.
    // DMA writes lptr + lane*16, i.e. ints wq + 4*lane .. +3  == tid*4..tid*4+3. Each
    // wave reads back exactly what it staged -> no cross-wave sync needed.
    const int wq = (tid >> 6) * 256;

    // Stage row r's quarter for this wave into dbuf[b][slot].
#define STAGE(r, b, slot)                                                              \
    __builtin_amdgcn_global_load_lds((const AS1 void*)(yrow + (size_t)(r) * N + tid * 4), \
                                     (AS3 void*)(&dbuf[b][slot][wq]), 16, 0, 0)

    int acc0 = 0, acc1 = 0, acc2 = 0, acc3 = 0;
    int sx = 0;

    // Prologue: stage super-iter 0's DMA rows (0,1) into buf 0.
    STAGE(0, 0, 0);
    STAGE(1, 0, 1);

    int b = 0;
#pragma unroll 4
    for (int s = 0; s < KCHUNK / 4; ++s) {
        const int r = 4 * s;
        // Issue next super-iter's DMA rows early (deep in flight).
        if (s + 1 < KCHUNK / 4) {
            STAGE(r + 4, b ^ 1, 0);
            STAGE(r + 5, b ^ 1, 1);
        }
        // Direct path: rows r+2, r+3 straight to VGPRs (compiler-pipelined).
        ivec4 v2 = __builtin_nontemporal_load((const ivec4*)(yrow + (size_t)(r + 2) * N) + tid);
        ivec4 v3 = __builtin_nontemporal_load((const ivec4*)(yrow + (size_t)(r + 3) * N) + tid);
        // DMA path: rows r, r+1 staged one super-iter ago (compiler inserts the
        // vmcnt needed between the LDS-DMA and this ds_read).
        ivec4 u0 = *(const ivec4*)&dbuf[b][0][tid * 4];
        ivec4 u1 = *(const ivec4*)&dbuf[b][1][tid * 4];

        const int a0 = xs[r], a1 = xs[r + 1], a2 = xs[r + 2], a3 = xs[r + 3];
        sx += a0 + a1 + a2 + a3;
        acc0 += a0 * u0.x + a1 * u1.x + a2 * v2.x + a3 * v3.x;
        acc1 += a0 * u0.y + a1 * u1.y + a2 * v2.y + a3 * v3.y;
        acc2 += a0 * u0.z + a1 * u1.z + a2 * v2.z + a3 * v3.z;
        acc3 += a0 * u0.w + a1 * u1.w + a2 * v2.w + a3 * v3.w;
        b ^= 1;
    }
#undef STAGE

    // Fold this chunk's zero-point correction -> reduce stays a pure sum.
    const int corr = Y_ZP * sx;
    ivec4 p;
    p.x = acc0 - corr;
    p.y = acc1 - corr;
    p.z = acc2 - corr;
    p.w = acc3 - corr;
    const int col4 = nb * (COLS_PER_BLOCK / 4) + tid;
    ws[(size_t)kc * N4 + col4] = p;
}

// Single-launch reduce over 128 partials per col4 (verified R7/R8).
constexpr int RBLK = 128;
constexpr int CPB  = N4 / RBLK;             // 32 col4 per block
constexpr int GRP  = BLOCK / CPB;           // 8 k-groups
constexpr int PER  = SPLIT_K / GRP;         // 16 partials per thread

__global__ __launch_bounds__(BLOCK) void qgemv_reduce(const ivec4* __restrict__ ws,
                                                      float* __restrict__ out) {
    __shared__ ivec4 red[GRP][CPB];         // 4 KiB
    const int c = threadIdx.x % CPB;
    const int g = threadIdx.x / CPB;
    const int col4 = blockIdx.x * CPB + c;

    int sx = 0, sy = 0, sz = 0, sw = 0;
#pragma unroll
    for (int i = 0; i < PER; ++i) {
        ivec4 v = ws[(size_t)(g * PER + i) * N4 + col4];
        sx += v.x; sy += v.y; sz += v.z; sw += v.w;
    }
    ivec4 p; p.x = sx; p.y = sy; p.z = sz; p.w = sw;
    red[g][c] = p;
    __syncthreads();

    if (g == 0) {
        ivec4 t = red[0][c];
#pragma unroll
        for (int gg = 1; gg < GRP; ++gg) {
            ivec4 v = red[gg][c];
            t.x += v.x; t.y += v.y; t.z += v.z; t.w += v.w;
        }
        const float s = X_SCALE * Y_SCALE;
        float4 o;
        o.x = s * (float)t.x;
        o.y = s * (float)t.y;
        o.z = s * (float)t.z;
        o.w = s * (float)t.w;
        ((float4*)out)[col4] = o;
    }
}

extern "C" void kernel_launch(void* const* d_in, const int* in_sizes, int n_in,
                              void* d_out, int out_size, void* d_ws, size_t ws_size,
                              hipStream_t stream) {
    const int* x = (const int*)d_in[0];
    const int* y = (const int*)d_in[1];
    float* out = (float*)d_out;
    ivec4* ws = (ivec4*)d_ws;   // 128 x 4096 x 16 B = 8 MiB of the workspace

    qgemv_partial<<<SPLIT_K * NBLK_N, BLOCK, 0, stream>>>(x, y, ws);
    qgemv_reduce<<<RBLK, BLOCK, 0, stream>>>(ws, out);
}

// Round 6
// 656.178 us; speedup vs baseline: 1.0676x; 1.0676x over previous
//
#include <hip/hip_runtime.h>

// Quantized vector-matrix multiply: out[n] = sum_k (x[k]-Xzp)*Xs * (y[k,n]-Yzp)*Ys
// Exact-integer reformulation:
//   out[n] = Xs*Ys * ( sum_k xs[k]*y[k,n] - Yzp*sum_k xs[k] ),  xs = x - X_ZP
// Full-K |acc| <= 8192*152*127 + 18*8192*152 ~ 1.8e8 -> int32-exact even summed
// across all 128 split-K contributions.
//
// R9->R10: FUSE REDUCE VIA NATIVE INT ATOMICS + GET THE KERNEL MEASURED.
// Five rounds of read-side levers (stripes/chunks/sweep, NT/cached, LDS-DMA)
// all land at ~1.7 TB/s effective; the main kernel has never appeared in the
// top-5 counter rows (fills at ~330-341 us crowd it out), so its FETCH_SIZE /
// VALUBusy / Occupancy are still unmeasured. This round: (1) drop the 8 MiB
// ws partial write + 8 MiB reduce read -- each block atomicAdds its 4 exact
// int32 results straight into a 64 KB accumulator (native global_atomic_add,
// deterministic, overlaps the tail of other blocks' loads) zeroed by a
// capturable hipMemsetAsync; (2) tiny 16-block kernel scales int->fp32;
// (3) corr = Y_ZP * sum(xs) is block-uniform -> computed once after the main
// loop instead of 64 in-loop adds per thread. Partial body otherwise R5's
// proven best: NT loads, 4 KiB stripes, rotation, 8 blocks/CU.

constexpr int K = 8192;
constexpr int N = 16384;
constexpr float X_SCALE = 0.0215f;
constexpr int   X_ZP    = -25;
constexpr float Y_SCALE = 0.0176f;
constexpr int   Y_ZP    = 18;

constexpr int BLOCK = 256;
constexpr int COLS_PER_BLOCK = 1024;           // int32 columns per block (4 KiB/row)
constexpr int NBLK_N = N / COLS_PER_BLOCK;     // 16
constexpr int SPLIT_K = 128;                   // 2048 blocks -> 8 blocks/CU
constexpr int KCHUNK = K / SPLIT_K;            // 64 rows per block
constexpr int N4 = N / 4;                      // vec4 columns per row

typedef int ivec4 __attribute__((ext_vector_type(4)));

__global__ __launch_bounds__(BLOCK, 8) void qgemv_fused(const int* __restrict__ x,
                                                        const ivec4* __restrict__ y,
                                                        int* __restrict__ acc) {
    __shared__ int xs[KCHUNK];

    const int nb = blockIdx.x % NBLK_N;
    const int kc = blockIdx.x / NBLK_N;
    const int k0 = kc * KCHUNK;

    if (threadIdx.x < KCHUNK)
        xs[threadIdx.x] = x[k0 + threadIdx.x] - X_ZP;
    __syncthreads();

    const int col4 = nb * (COLS_PER_BLOCK / 4) + threadIdx.x;
    const ivec4* __restrict__ yv = y + (size_t)k0 * N4 + col4;

    // Per-block rotation phase (order-independent sum): spread concurrent blocks'
    // instantaneous footprint across HBM interleave units.
    const int r0 = (13 * kc + 7 * nb) & (KCHUNK - 1);

    int acc0 = 0, acc1 = 0, acc2 = 0, acc3 = 0;

#pragma unroll 8
    for (int i = 0; i < KCHUNK; ++i) {
        int k = r0 + i;
        if (k >= KCHUNK) k -= KCHUNK;
        ivec4 v = __builtin_nontemporal_load(&yv[(size_t)k * N4]);
        int a = xs[k];
        acc0 += a * v.x;
        acc1 += a * v.y;
        acc2 += a * v.z;
        acc3 += a * v.w;
    }

    // corr is block-uniform: compute once from LDS (off the critical path).
    int sx = 0;
#pragma unroll
    for (int i = 0; i < KCHUNK; ++i) sx += xs[i];
    const int corr = Y_ZP * sx;

    // Exact int32 accumulation across the 128 k-chunks via native atomics.
    int* o = acc + 4 * (size_t)col4;
    atomicAdd(o + 0, acc0 - corr);
    atomicAdd(o + 1, acc1 - corr);
    atomicAdd(o + 2, acc2 - corr);
    atomicAdd(o + 3, acc3 - corr);
}

// Tiny finish: scale int sums to fp32. 16 blocks x 256 threads, vec4 I/O.
__global__ __launch_bounds__(BLOCK) void qgemv_finish(const ivec4* __restrict__ acc,
                                                      float* __restrict__ out) {
    const int t = blockIdx.x * BLOCK + threadIdx.x;   // 0 .. N4-1
    ivec4 v = acc[t];
    const float s = X_SCALE * Y_SCALE;
    float4 o;
    o.x = s * (float)v.x;
    o.y = s * (float)v.y;
    o.z = s * (float)v.z;
    o.w = s * (float)v.w;
    ((float4*)out)[t] = o;
}

extern "C" void kernel_launch(void* const* d_in, const int* in_sizes, int n_in,
                              void* d_out, int out_size, void* d_ws, size_t ws_size,
                              hipStream_t stream) {
    const int* x = (const int*)d_in[0];
    const ivec4* y = (const ivec4*)d_in[1];
    float* out = (float*)d_out;
    int* acc = (int*)d_ws;                     // first 64 KB of workspace

    // Zero the accumulator (async, stream-ordered, graph-capturable).
    hipMemsetAsync(acc, 0, (size_t)N * sizeof(int), stream);
    qgemv_fused<<<SPLIT_K * NBLK_N, BLOCK, 0, stream>>>(x, y, acc);
    qgemv_finish<<<N4 / BLOCK, BLOCK, 0, stream>>>((const ivec4*)acc, out);
}